// Round 13
// baseline (479.736 us; speedup 1.0000x reference)
//
#include <hip/hip_runtime.h>
#include <math.h>

// MarginDevianceLoss: N=4096, D=256, K=8, targets = i/8.
// Outputs: [loss, prec, pos_d, neg_d] fp32.
//
// R13: ONE persistent kernel (1024 blocks = exactly 4/CU, co-residency forced
// by __launch_bounds__(256,4): VGPR<=128, LDS 17.5KB*4 <= 160KB) + tree device
// barriers (32 group counters -> root; 32 same-address atomics each ~0.4us —
// NOT R7's 20480). Monotonic phase counters, zeroed by one hipMemsetAsync.
// Phases: convert(X->Xf frag-major bf16) |B1| pass1 GEMM (glds-staged B,
// sum/sumsq + diag classSim -> partials) |B2| per-block stats (inter/thresh
// kept in LDS; by==0 writes posLoss/psum/nsum) -> pass2 GEMM (filter+poly-
// softplus -> cnt/nls partials) |B3| finalA (4 rows/block, 32-way striped
// float atomics) |B4(arrive-only for most)| block(0,0) finalB -> out.
// R12 lesson kept: NO inline fp32 staging (scattered reads thrash per-XCD L2).

#define NROWS 4096
#define DIM   256
#define KCLS  8
#define NJB   32

typedef __bf16 bf16x8 __attribute__((ext_vector_type(8)));
typedef float  f32x4  __attribute__((ext_vector_type(4)));

union U4B { uint4 u; bf16x8 v; };

// log(1+exp(z)) = max(z,0) + ln2*log2(1+exp2(-|z|*log2e)); quartic log2(1+u).
__device__ __forceinline__ float softplus_poly(float z) {
    float u = __builtin_exp2f(-1.4426950408889634f * __builtin_fabsf(z));
    float p = u * (1.4426950f + u * (-0.6949650f + u * (0.3454302f + u * -0.0931600f)));
    return fmaf(p, 0.6931471805599453f, fmaxf(z, 0.f));
}

__device__ __forceinline__ unsigned int pack_bf2(float a, float b) {
    unsigned int ua = __float_as_uint(a);
    unsigned int ub = __float_as_uint(b);
    ua = (ua + 0x7FFFu + ((ua >> 16) & 1u)) >> 16;   // RNE
    ub = (ub + 0x7FFFu + ((ub >> 16) & 1u)) >> 16;
    return ua | (ub << 16);
}

__device__ __forceinline__ uint4 pack8(float4 a, float4 b) {
    uint4 o;
    o.x = pack_bf2(a.x, a.y);
    o.y = pack_bf2(a.z, a.w);
    o.z = pack_bf2(b.x, b.y);
    o.w = pack_bf2(b.z, b.w);
    return o;
}

__device__ __forceinline__ void glds16(const unsigned short* g, unsigned short* l) {
    __builtin_amdgcn_global_load_lds(
        (const __attribute__((address_space(1))) void*)g,
        (__attribute__((address_space(3))) void*)l, 16, 0, 0);
}

// Tree device barrier. Monotonic counters (no reset). cnt1[g] stride 16 uints
// (64 B) to split L2 lines. After phase p: cnt1[g]==32p, cnt2==32p, flag==p.
__device__ __forceinline__ void devBarrier(unsigned* cnt1, unsigned* cnt2,
                                           unsigned* flag, unsigned phase,
                                           bool wait)
{
    __syncthreads();
    if (threadIdx.x == 0) {
        __threadfence();   // flush this block's stores toward LLC
        unsigned o = __hip_atomic_fetch_add(&cnt1[blockIdx.y * 16], 1u,
                         __ATOMIC_ACQ_REL, __HIP_MEMORY_SCOPE_AGENT);
        if (o == phase * 32u - 1u) {                 // group complete
            unsigned r = __hip_atomic_fetch_add(cnt2, 1u,
                             __ATOMIC_ACQ_REL, __HIP_MEMORY_SCOPE_AGENT);
            if (r == phase * 32u - 1u)               // all groups complete
                __hip_atomic_store(flag, phase, __ATOMIC_RELEASE,
                                   __HIP_MEMORY_SCOPE_AGENT);
        }
        if (wait) {
            while (__hip_atomic_load(flag, __ATOMIC_ACQUIRE,
                                     __HIP_MEMORY_SCOPE_AGENT) < phase)
                __builtin_amdgcn_s_sleep(8);
            __threadfence();   // invalidate stale caches before phase reads
        }
    }
    __syncthreads();
}

__global__ __launch_bounds__(256, 4)
void fused_kernel(const float* __restrict__ X,
                  unsigned short* __restrict__ Xf,
                  float* __restrict__ sumPart,  float* __restrict__ sqPart,
                  float* __restrict__ cntPart,  float* __restrict__ nlsPart,
                  float* __restrict__ classSim,
                  float* __restrict__ posLossA,
                  float* __restrict__ rowPsum,  float* __restrict__ rowNsum,
                  unsigned* __restrict__ cnt1,  unsigned* __restrict__ cnt2,
                  unsigned* __restrict__ flag,  float* __restrict__ accf,
                  float* __restrict__ out)
{
    __shared__ __align__(16) unsigned short Bs[2][8][512];   // 16 KB
    __shared__ float interL[128], threshL[128];              // 1 KB
    __shared__ float fl[4][4];

    const int t    = threadIdx.x;
    const int lane = t & 63;
    const int wave = t >> 6;
    const int quad = lane >> 4;
    const int n16  = lane & 15;
    const int bx   = blockIdx.x;
    const int by   = blockIdx.y;
    const int i0   = (bx * 8 + wave * 2) * 16;   // wave's first row
    const int j0   = by * 128;
    const int jt0  = by * 8;
    const bool diag = (bx == by);

    // ================= phase 0: convert X -> Xf (128 slices/block) ==========
    {
        int bid = by * 32 + bx;
        if (t < 128) {
            int v  = bid * 128 + t;
            int tile = v >> 9;
            int kf   = (v >> 6) & 7;
            int l    = v & 63;
            int row  = tile * 16 + (l & 15);
            int c4   = kf * 8 + (l >> 4) * 2;
            const float4* X4 = reinterpret_cast<const float4*>(X);
            float4 a = X4[row * 64 + c4];
            float4 b = X4[row * 64 + c4 + 1];
            reinterpret_cast<uint4*>(Xf)[v] = pack8(a, b);
        }
    }
    devBarrier(cnt1, cnt2, flag, 1, true);

    // ================= A fragments (shared by both GEMM passes) =============
    bf16x8 afrag[2][8];
    #pragma unroll
    for (int tt = 0; tt < 2; ++tt) {
        const unsigned short* ap =
            Xf + ((size_t)(bx * 8 + wave * 2 + tt) * 8) * 512 + lane * 8;
        #pragma unroll
        for (int kf = 0; kf < 8; ++kf)
            afrag[tt][kf] = *reinterpret_cast<const bf16x8*>(ap + kf * 512);
    }

    auto stage = [&](int buf, int jt) {
        const unsigned short* src =
            Xf + ((size_t)(jt0 + jt) * 8 + wave * 2) * 512 + lane * 8;
        glds16(src,       &Bs[buf][wave * 2][0]);
        glds16(src + 512, &Bs[buf][wave * 2 + 1][0]);
    };

    // ================= phase 1: GEMM pass 1 (sum/sumsq + classSim) ==========
    {
        float accA[2][4] = {};
        float accB[2][4] = {};
        stage(0, 0);
        __syncthreads();
        int buf = 0;
        #pragma unroll 1
        for (int jt = 0; jt < 8; ++jt) {
            if (jt < 7) stage(buf ^ 1, jt + 1);
            bf16x8 bfr[8];
            #pragma unroll
            for (int kf = 0; kf < 8; ++kf)
                bfr[kf] = *reinterpret_cast<const bf16x8*>(&Bs[buf][kf][lane * 8]);
            f32x4 ac[2] = {{0.f,0.f,0.f,0.f},{0.f,0.f,0.f,0.f}};
            #pragma unroll
            for (int kf = 0; kf < 8; ++kf) {
                ac[0] = __builtin_amdgcn_mfma_f32_16x16x32_bf16(afrag[0][kf], bfr[kf], ac[0], 0,0,0);
                ac[1] = __builtin_amdgcn_mfma_f32_16x16x32_bf16(afrag[1][kf], bfr[kf], ac[1], 0,0,0);
            }
            #pragma unroll
            for (int tt = 0; tt < 2; ++tt)
                #pragma unroll
                for (int r = 0; r < 4; ++r) {
                    float s = ac[tt][r];
                    accA[tt][r] += s;
                    accB[tt][r] = fmaf(s, s, accB[tt][r]);
                }
            if (diag) {
                int j = j0 + jt * 16 + n16;
                #pragma unroll
                for (int tt = 0; tt < 2; ++tt)
                    #pragma unroll
                    for (int r = 0; r < 4; ++r) {
                        int i = i0 + tt * 16 + quad * 4 + r;
                        if (((i ^ j) >> 3) == 0)
                            classSim[i * KCLS + (j & 7)] = ac[tt][r];
                    }
            }
            __syncthreads();
            buf ^= 1;
        }
        #pragma unroll
        for (int tt = 0; tt < 2; ++tt) {
            #pragma unroll
            for (int r = 0; r < 4; ++r) {
                #pragma unroll
                for (int m = 8; m >= 1; m >>= 1) {
                    accA[tt][r] += __shfl_xor(accA[tt][r], m);
                    accB[tt][r] += __shfl_xor(accB[tt][r], m);
                }
            }
            if (n16 == 0) {
                int base = by * NROWS + i0 + tt * 16 + quad * 4;
                float4 va = {accA[tt][0], accA[tt][1], accA[tt][2], accA[tt][3]};
                float4 vb = {accB[tt][0], accB[tt][1], accB[tt][2], accB[tt][3]};
                *reinterpret_cast<float4*>(&sumPart[base]) = va;
                *reinterpret_cast<float4*>(&sqPart[base])  = vb;
            }
        }
    }
    devBarrier(cnt1, cnt2, flag, 2, true);

    // ================= phase 2: per-block stats for its 128 rows ============
    if (t < 128) {
        const int i = bx * 128 + t;
        const int self = i & 7;
        float S = 0.f, SQ = 0.f;
        #pragma unroll
        for (int b = 0; b < NJB; ++b) {
            S  += sumPart[b * NROWS + i];
            SQ += sqPart[b * NROWS + i];
        }
        float4 c0 = reinterpret_cast<const float4*>(classSim)[i * 2];
        float4 c1 = reinterpret_cast<const float4*>(classSim)[i * 2 + 1];
        float cs[KCLS] = {c0.x, c0.y, c0.z, c0.w, c1.x, c1.y, c1.z, c1.w};
        float sii = cs[self];
        float psum = 0.f, psq = 0.f, pmin = 1e30f;
        #pragma unroll
        for (int m = 0; m < KCLS; ++m) {
            if (m != self) {
                psum += cs[m];
                psq  += cs[m] * cs[m];
                pmin  = fminf(pmin, cs[m]);
            }
        }
        const float p = (float)(KCLS - 1);
        const float mneg = (float)(NROWS - KCLS);
        float nsum = S - psum - sii;
        float nsq  = SQ - psq - sii * sii;
        float pmean = psum / p;
        float pstd  = sqrtf(fmaxf(psq / p - pmean * pmean, 0.f));
        float nmean = nsum / mneg;
        float nstd  = sqrtf(fmaxf(nsq / mneg - nmean * nmean, 0.f));
        float inter  = 0.8f * (nstd * pmean + pstd * nmean) / (pstd + nstd) + 0.1f;
        float pl = 0.f;
        #pragma unroll
        for (int m = 0; m < KCLS; ++m) {
            if (m != self) pl += softplus_poly(-10.f * (cs[m] - inter));
        }
        pl *= 0.2f / p;
        interL[t]  = inter;
        threshL[t] = pmin - 0.05f;
        if (by == 0) {
            posLossA[i] = pl;
            rowPsum[i]  = psum;
            rowNsum[i]  = nsum;
        }
    }
    __syncthreads();   // interL/threshL visible to all waves

    // ================= phase 3: GEMM pass 2 (filter + softplus) =============
    {
        float c40[2][4], threshR[2][4];
        int icls[2];
        #pragma unroll
        for (int tt = 0; tt < 2; ++tt) {
            int lbase = wave * 32 + tt * 16 + quad * 4;       // local row
            icls[tt] = (i0 + tt * 16 + quad * 4) >> 3;
            #pragma unroll
            for (int r = 0; r < 4; ++r) {
                c40[tt][r]     = -40.f * interL[lbase + r];
                threshR[tt][r] = threshL[lbase + r];
            }
        }
        float accA[2][4] = {};
        float accB[2][4] = {};
        stage(0, 0);
        __syncthreads();
        int buf = 0;
        #pragma unroll 1
        for (int jt = 0; jt < 8; ++jt) {
            if (jt < 7) stage(buf ^ 1, jt + 1);
            bf16x8 bfr[8];
            #pragma unroll
            for (int kf = 0; kf < 8; ++kf)
                bfr[kf] = *reinterpret_cast<const bf16x8*>(&Bs[buf][kf][lane * 8]);
            f32x4 ac[2] = {{0.f,0.f,0.f,0.f},{0.f,0.f,0.f,0.f}};
            #pragma unroll
            for (int kf = 0; kf < 8; ++kf) {
                ac[0] = __builtin_amdgcn_mfma_f32_16x16x32_bf16(afrag[0][kf], bfr[kf], ac[0], 0,0,0);
                ac[1] = __builtin_amdgcn_mfma_f32_16x16x32_bf16(afrag[1][kf], bfr[kf], ac[1], 0,0,0);
            }
            const int jcls = (j0 + jt * 16 + n16) >> 3;
            #pragma unroll
            for (int tt = 0; tt < 2; ++tt) {
                const bool neg = (icls[tt] != jcls);
                #pragma unroll
                for (int r = 0; r < 4; ++r) {
                    float s  = ac[tt][r];
                    float sp = softplus_poly(fmaf(40.f, s, c40[tt][r]));
                    float m  = (neg && s > threshR[tt][r]) ? 1.f : 0.f;
                    accA[tt][r] += m;
                    accB[tt][r] = fmaf(m, sp, accB[tt][r]);
                }
            }
            __syncthreads();
            buf ^= 1;
        }
        #pragma unroll
        for (int tt = 0; tt < 2; ++tt) {
            #pragma unroll
            for (int r = 0; r < 4; ++r) {
                #pragma unroll
                for (int m = 8; m >= 1; m >>= 1) {
                    accA[tt][r] += __shfl_xor(accA[tt][r], m);
                    accB[tt][r] += __shfl_xor(accB[tt][r], m);
                }
            }
            if (n16 == 0) {
                int base = by * NROWS + i0 + tt * 16 + quad * 4;
                float4 va = {accA[tt][0], accA[tt][1], accA[tt][2], accA[tt][3]};
                float4 vb = {accB[tt][0], accB[tt][1], accB[tt][2], accB[tt][3]};
                *reinterpret_cast<float4*>(&cntPart[base]) = va;
                *reinterpret_cast<float4*>(&nlsPart[base]) = vb;
            }
        }
    }
    devBarrier(cnt1, cnt2, flag, 3, true);

    // ================= phase 4: finalA — 4 rows per block ===================
    {
        const int gid = by * 32 + bx;
        const int row = gid * 4 + wave;          // wave handles one row
        float v = (lane < 32) ? cntPart[lane * NROWS + row]
                              : nlsPart[(lane - 32) * NROWS + row];
        #pragma unroll
        for (int m = 1; m <= 16; m <<= 1) v += __shfl_xor(v, m);
        float vo = __shfl_xor(v, 32);            // lane<32: v=c, vo=n
        if (lane == 0) {
            float c = v, n = vo;
            float rl = (c > 0.f) ? (posLossA[row] + 0.05f * n / c) : 0.f;
            fl[wave][0] = rl;
            fl[wave][1] = (c > 0.f) ? 0.f : 1.f;
            fl[wave][2] = rowPsum[row];
            fl[wave][3] = rowNsum[row];
        }
        __syncthreads();
        if (t < 4) {
            float s = fl[0][t] + fl[1][t] + fl[2][t] + fl[3][t];
            atomicAdd(&accf[bx * 16 + t], s);    // 32 adds/address, striped
        }
    }
    devBarrier(cnt1, cnt2, flag, 4, (bx == 0 && by == 0));

    // ================= phase 5: finalB by block (0,0) =======================
    if (bx == 0 && by == 0) {
        int k = t >> 6, l = t & 63;
        if (l < 32) {
            float v = atomicAdd(&accf[l * 16 + k], 0.f);   // coherent read
            #pragma unroll
            for (int m = 1; m <= 16; m <<= 1) v += __shfl_xor(v, m);
            if (l == 0) {
                if (k == 0) out[0] = v / (float)NROWS;
                if (k == 1) out[1] = v / (float)NROWS;
                if (k == 2) out[2] = v / ((float)NROWS * (float)(KCLS - 1));
                if (k == 3) out[3] = v / ((float)NROWS * (float)(NROWS - KCLS));
            }
        }
    }
}

extern "C" void kernel_launch(void* const* d_in, const int* in_sizes, int n_in,
                              void* d_out, int out_size, void* d_ws, size_t ws_size,
                              hipStream_t stream)
{
    const float* X = (const float*)d_in[0];

    // control region (memset to 0): cnt1[32*16] | cnt2(16) | flag(16) | accf[32*16]
    unsigned* cnt1 = (unsigned*)d_ws;                    // 2048 B
    unsigned* cnt2 = cnt1 + 32 * 16;                     // 64 B line
    unsigned* flag = cnt2 + 16;                          // 64 B line
    float*    accf = (float*)(flag + 16);                // 2048 B
    const size_t ctrlBytes = (32 * 16 + 16 + 16 + 32 * 16) * 4;

    float* fp       = accf + 32 * 16;
    float* sumPart  = fp;                                // 32*4096
    float* sqPart   = sumPart + NJB * NROWS;
    float* cntPart  = sqPart  + NJB * NROWS;
    float* nlsPart  = cntPart + NJB * NROWS;
    float* classSim = nlsPart + NJB * NROWS;             // 4096*8
    float* posLossA = classSim + NROWS * KCLS;
    float* rowPsum  = posLossA + NROWS;
    float* rowNsum  = rowPsum + NROWS;
    unsigned short* Xf = (unsigned short*)(rowNsum + NROWS);   // 2 MB
    // total ws use: ~4.4 MB

    (void)hipMemsetAsync(d_ws, 0, ctrlBytes, stream);

    dim3 grid(32, 32);   // 1024 blocks = exactly 4/CU (launch_bounds(256,4))
    fused_kernel<<<grid, 256, 0, stream>>>(X, Xf,
                                           sumPart, sqPart, cntPart, nlsPart,
                                           classSim, posLossA, rowPsum, rowNsum,
                                           cnt1, cnt2, flag, accf,
                                           (float*)d_out);
}

// Round 14
// 97.292 us; speedup vs baseline: 4.9309x; 4.9309x over previous
//
#include <hip/hip_runtime.h>
#include <math.h>

// MarginDevianceLoss: N=4096, D=256, K=8, targets = i/8.
// Outputs: [loss, prec, pos_d, neg_d] fp32.
//
// R14 = R11 (best: 101 us) + R12's verified finalAB fusion (16-block
// last-block-done; 16 counter atomics — fine, unlike R7's 20480 or R13's
// 1024-block grid barriers which both disastrously regressed).
// Structure: convert (Xf frag-major bf16, zeroes finalAB counter) ->
// gemm pass1 (glds-staged B, sum/sumsq + diag classSim -> partials) ->
// stats (per-row inter/thresh/posLoss/psum/nsum) ->
// gemm pass2 (branchless filter + poly-softplus -> cnt/nls partials) ->
// finalAB (row reduce + 4 outputs). 5 dispatches, no big atomic fan-in.

#define NROWS 4096
#define DIM   256
#define KCLS  8
#define NJB   32     // j-blocks = partials per row

typedef __bf16 bf16x8 __attribute__((ext_vector_type(8)));
typedef float  f32x4  __attribute__((ext_vector_type(4)));

// log(1+exp(z)) = max(z,0) + ln2 * log2(1 + exp2(-|z|*log2e));
// log2(1+u), u in (0,1], quartic fit (abs err <= ~4e-4).
__device__ __forceinline__ float softplus_poly(float z) {
    float u = __builtin_exp2f(-1.4426950408889634f * __builtin_fabsf(z));
    float p = u * (1.4426950f + u * (-0.6949650f + u * (0.3454302f + u * -0.0931600f)));
    return fmaf(p, 0.6931471805599453f, fmaxf(z, 0.f));
}

__device__ __forceinline__ unsigned int pack_bf2(float a, float b) {
    unsigned int ua = __float_as_uint(a);
    unsigned int ub = __float_as_uint(b);
    ua = (ua + 0x7FFFu + ((ua >> 16) & 1u)) >> 16;   // RNE
    ub = (ub + 0x7FFFu + ((ub >> 16) & 1u)) >> 16;
    return ua | (ub << 16);
}

__device__ __forceinline__ void glds16(const unsigned short* g, unsigned short* l) {
    // HW semantics: each lane reads 16 B at its own g; LDS dest = uniform l + lane*16.
    __builtin_amdgcn_global_load_lds(
        (const __attribute__((address_space(1))) void*)g,
        (__attribute__((address_space(3))) void*)l, 16, 0, 0);
}

// X (fp32 row-major) -> Xf (bf16 fragment-major):
// Xf[((tile*8 + kf)*64 + lane)*8 + e] = X[tile*16 + (lane&15)][kf*32 + (lane>>4)*8 + e]
// Also zeroes the finalAB done-counter (used 3 dispatches later).
__global__ __launch_bounds__(256)
void convert_kernel(const float* __restrict__ X, unsigned short* __restrict__ Xf,
                    unsigned int* __restrict__ counter)
{
    int v = blockIdx.x * 256 + threadIdx.x;    // 131072 fragment-slices of 16 B
    if (v == 0) *counter = 0u;
    int tile = v >> 9;
    int kf   = (v >> 6) & 7;
    int lane = v & 63;
    int row  = tile * 16 + (lane & 15);
    int c4   = kf * 8 + (lane >> 4) * 2;       // col/4
    const float4* X4 = reinterpret_cast<const float4*>(X);
    float4 a = X4[row * 64 + c4];
    float4 b = X4[row * 64 + c4 + 1];
    uint4 o;
    o.x = pack_bf2(a.x, a.y);
    o.y = pack_bf2(a.z, a.w);
    o.z = pack_bf2(b.x, b.y);
    o.w = pack_bf2(b.z, b.w);
    reinterpret_cast<uint4*>(Xf)[v] = o;
}

// Grid (32,32). Block: 4 waves; wave w -> i-tiles {bx*8+w*2, +1} (A cached in
// regs, K=256). All waves sweep j-tiles [by*8,+8); B staged via LDS
// (global_load_lds, double-buffered, 2 frags/wave/tile).
// PASS 1 (STATS=1): sum/sumsq epilogue + diag classSim -> float4 partials.
// PASS 2 (STATS=0): branchless filter + poly-softplus -> cnt/nls partials.
template<int STATS>
__global__ __launch_bounds__(256)
void gemm_pass_kernel(const unsigned short* __restrict__ Xf,
                      const float* __restrict__ interA,
                      const float* __restrict__ threshA,
                      float* __restrict__ outPartA,   // sumPart  / cntPart
                      float* __restrict__ outPartB,   // sqPart   / nlsPart
                      float* __restrict__ classSim)
{
    __shared__ __align__(16) unsigned short Bs[2][8][512];   // 2 x 8 KB

    const int lane = threadIdx.x & 63;
    const int wave = threadIdx.x >> 6;
    const int quad = lane >> 4;
    const int n16  = lane & 15;
    const int it0  = blockIdx.x * 8 + wave * 2;
    const int i0   = it0 * 16;
    const int j0   = blockIdx.y * 128;
    const int jt0  = blockIdx.y * 8;
    const bool diag = (blockIdx.x == blockIdx.y);

    // A fragments: 2 i-tiles x 8 k-frags, coalesced 1-KB global loads
    bf16x8 afrag[2][8];
    #pragma unroll
    for (int t = 0; t < 2; ++t) {
        const unsigned short* ap = Xf + ((size_t)(it0 + t) * 8) * 512 + lane * 8;
        #pragma unroll
        for (int kf = 0; kf < 8; ++kf)
            afrag[t][kf] = *reinterpret_cast<const bf16x8*>(ap + kf * 512);
    }

    float accA[2][4] = {};       // sI / cnt
    float accB[2][4] = {};       // sqI / nls
    float c40[2][4], threshR[2][4];
    int   icls[2];
    if constexpr (!STATS) {
        #pragma unroll
        for (int t = 0; t < 2; ++t) {
            icls[t] = (i0 + t * 16 + quad * 4) >> 3;   // rows quad*4..+3 share class
            #pragma unroll
            for (int r = 0; r < 4; ++r) {
                int i = i0 + t * 16 + quad * 4 + r;
                c40[t][r]     = -40.f * interA[i];
                threshR[t][r] = threshA[i];
            }
        }
    }

    // stage B frags for j-tile jt into buffer buf: wave w loads frags 2w,2w+1
    auto stage = [&](int buf, int jt) {
        const unsigned short* src =
            Xf + ((size_t)(jt0 + jt) * 8 + wave * 2) * 512 + lane * 8;
        glds16(src,       &Bs[buf][wave * 2][0]);
        glds16(src + 512, &Bs[buf][wave * 2 + 1][0]);
    };

    stage(0, 0);
    __syncthreads();

    int buf = 0;
    #pragma unroll 1
    for (int jt = 0; jt < 8; ++jt) {
        if (jt < 7) stage(buf ^ 1, jt + 1);

        bf16x8 bfr[8];
        #pragma unroll
        for (int kf = 0; kf < 8; ++kf)
            bfr[kf] = *reinterpret_cast<const bf16x8*>(&Bs[buf][kf][lane * 8]);

        f32x4 ac[2] = {{0.f, 0.f, 0.f, 0.f}, {0.f, 0.f, 0.f, 0.f}};
        #pragma unroll
        for (int kf = 0; kf < 8; ++kf) {
            ac[0] = __builtin_amdgcn_mfma_f32_16x16x32_bf16(afrag[0][kf], bfr[kf], ac[0], 0, 0, 0);
            ac[1] = __builtin_amdgcn_mfma_f32_16x16x32_bf16(afrag[1][kf], bfr[kf], ac[1], 0, 0, 0);
        }

        if constexpr (STATS) {
            #pragma unroll
            for (int t = 0; t < 2; ++t)
                #pragma unroll
                for (int r = 0; r < 4; ++r) {
                    float s = ac[t][r];
                    accA[t][r] += s;
                    accB[t][r] = fmaf(s, s, accB[t][r]);
                }
            if (diag) {                    // wave-uniform: 32/1024 blocks
                int j = j0 + jt * 16 + n16;
                #pragma unroll
                for (int t = 0; t < 2; ++t)
                    #pragma unroll
                    for (int r = 0; r < 4; ++r) {
                        int i = i0 + t * 16 + quad * 4 + r;
                        if (((i ^ j) >> 3) == 0)
                            classSim[i * KCLS + (j & 7)] = ac[t][r];
                    }
            }
        } else {
            const int jcls = (j0 + jt * 16 + n16) >> 3;
            #pragma unroll
            for (int t = 0; t < 2; ++t) {
                const bool neg = (icls[t] != jcls);
                #pragma unroll
                for (int r = 0; r < 4; ++r) {
                    float s  = ac[t][r];
                    float sp = softplus_poly(fmaf(40.f, s, c40[t][r]));
                    float m  = (neg && s > threshR[t][r]) ? 1.f : 0.f;
                    accA[t][r] += m;
                    accB[t][r] = fmaf(m, sp, accB[t][r]);
                }
            }
        }

        __syncthreads();    // drains glds for jt+1; frees buf for jt+2
        buf ^= 1;
    }

    // quad shuffle-reduce (16 lanes share rows) -> float4 partial stores
    #pragma unroll
    for (int t = 0; t < 2; ++t) {
        #pragma unroll
        for (int r = 0; r < 4; ++r) {
            #pragma unroll
            for (int m = 8; m >= 1; m >>= 1) {
                accA[t][r] += __shfl_xor(accA[t][r], m);
                accB[t][r] += __shfl_xor(accB[t][r], m);
            }
        }
        if (n16 == 0) {
            int base = blockIdx.y * NROWS + i0 + t * 16 + quad * 4;
            float4 va = {accA[t][0], accA[t][1], accA[t][2], accA[t][3]};
            float4 vb = {accB[t][0], accB[t][1], accB[t][2], accB[t][3]};
            *reinterpret_cast<float4*>(&outPartA[base]) = va;
            *reinterpret_cast<float4*>(&outPartB[base]) = vb;
        }
    }
}

// One thread per row: reduce 32 partials + classSim -> inter/thresh/posLoss/
// psum/nsum.
__global__ __launch_bounds__(256)
void stats_kernel(const float* __restrict__ sumPart,
                  const float* __restrict__ sqPart,
                  const float* __restrict__ classSim,
                  float* __restrict__ interA,
                  float* __restrict__ threshA,
                  float* __restrict__ posLossA,
                  float* __restrict__ rowPsum,
                  float* __restrict__ rowNsum)
{
    const int i = blockIdx.x * 256 + threadIdx.x;
    const int self = i & 7;

    float S = 0.f, SQ = 0.f;
    #pragma unroll
    for (int b = 0; b < NJB; ++b) {
        S  += sumPart[b * NROWS + i];
        SQ += sqPart[b * NROWS + i];
    }

    float4 c0 = reinterpret_cast<const float4*>(classSim)[i * 2];
    float4 c1 = reinterpret_cast<const float4*>(classSim)[i * 2 + 1];
    float cs[KCLS] = {c0.x, c0.y, c0.z, c0.w, c1.x, c1.y, c1.z, c1.w};

    float sii = cs[self];
    float psum = 0.f, psq = 0.f, pmin = 1e30f;
    #pragma unroll
    for (int m = 0; m < KCLS; ++m) {
        if (m != self) {
            psum += cs[m];
            psq  += cs[m] * cs[m];
            pmin  = fminf(pmin, cs[m]);
        }
    }
    const float p = (float)(KCLS - 1);            // 7
    const float mneg = (float)(NROWS - KCLS);     // 4088
    float nsum = S - psum - sii;
    float nsq  = SQ - psq - sii * sii;
    float pmean = psum / p;
    float pstd  = sqrtf(fmaxf(psq / p - pmean * pmean, 0.f));
    float nmean = nsum / mneg;
    float nstd  = sqrtf(fmaxf(nsq / mneg - nmean * nmean, 0.f));
    float inter  = 0.8f * (nstd * pmean + pstd * nmean) / (pstd + nstd) + 0.1f;

    float pl = 0.f;
    #pragma unroll
    for (int m = 0; m < KCLS; ++m) {
        if (m != self) pl += softplus_poly(-10.f * (cs[m] - inter));
    }
    pl *= 0.2f / p;

    interA[i]   = inter;
    threshA[i]  = pmin - 0.05f;
    posLossA[i] = pl;
    rowPsum[i]  = psum;
    rowNsum[i]  = nsum;
}

// 16 blocks x 256 threads; thread -> one row. Reduce cnt/nls partials ->
// rowLoss/rowInv, block-reduce 4 sums, last block combines -> out.
__global__ __launch_bounds__(256)
void finalAB_kernel(const float* __restrict__ cntPart,
                    const float* __restrict__ nlsPart,
                    const float* __restrict__ posLossA,
                    const float* __restrict__ rowPsum,
                    const float* __restrict__ rowNsum,
                    float* __restrict__ blkPart,      // 16*4 floats
                    unsigned int* __restrict__ counter,
                    float* __restrict__ out)
{
    const int t = threadIdx.x;
    const int i = blockIdx.x * 256 + t;

    float c = 0.f, n = 0.f;
    #pragma unroll
    for (int b = 0; b < NJB; ++b) {
        c += cntPart[b * NROWS + i];
        n += nlsPart[b * NROWS + i];
    }
    float loss = (c > 0.f) ? (posLossA[i] + 0.05f * n / c) : 0.f;
    float inv  = (c > 0.f) ? 0.f : 1.f;
    float pd   = rowPsum[i];
    float nd   = rowNsum[i];

    #pragma unroll
    for (int off = 32; off > 0; off >>= 1) {
        loss += __shfl_down(loss, off);
        inv  += __shfl_down(inv, off);
        pd   += __shfl_down(pd, off);
        nd   += __shfl_down(nd, off);
    }
    __shared__ float sl[4], si[4], sp[4], sq[4];
    int w = t >> 6;
    if ((t & 63) == 0) { sl[w] = loss; si[w] = inv; sp[w] = pd; sq[w] = nd; }
    __syncthreads();
    if (t == 0) {
        blkPart[blockIdx.x * 4 + 0] = sl[0] + sl[1] + sl[2] + sl[3];
        blkPart[blockIdx.x * 4 + 1] = si[0] + si[1] + si[2] + si[3];
        blkPart[blockIdx.x * 4 + 2] = sp[0] + sp[1] + sp[2] + sp[3];
        blkPart[blockIdx.x * 4 + 3] = sq[0] + sq[1] + sq[2] + sq[3];
        __threadfence();
        unsigned int old = atomicAdd(counter, 1u);
        sl[0] = (old == 15u) ? 1.f : 0.f;       // reuse LDS as flag
    }
    __syncthreads();
    if (sl[0] != 0.f && t < 64) {
        // last block: coherent read of all 64 partials (distinct addresses)
        float v = atomicAdd(&blkPart[t], 0.f);
        #pragma unroll
        for (int off = 4; off < 64; off <<= 1) v += __shfl_xor(v, off);
        // lanes 0..3 now hold totals: loss, inv, psum, nsum
        if (t == 0) out[0] = v / (float)NROWS;
        if (t == 1) out[1] = v / (float)NROWS;
        if (t == 2) out[2] = v / ((float)NROWS * (float)(KCLS - 1));
        if (t == 3) out[3] = v / ((float)NROWS * (float)(NROWS - KCLS));
    }
}

extern "C" void kernel_launch(void* const* d_in, const int* in_sizes, int n_in,
                              void* d_out, int out_size, void* d_ws, size_t ws_size,
                              hipStream_t stream)
{
    const float* X = (const float*)d_in[0];

    float* ws       = (float*)d_ws;
    float* sumPart  = ws;                                   // 32*4096
    float* sqPart   = sumPart + NJB * NROWS;                // 32*4096
    float* cntPart  = sqPart  + NJB * NROWS;                // 32*4096
    float* nlsPart  = cntPart + NJB * NROWS;                // 32*4096
    float* classSim = nlsPart + NJB * NROWS;                // 4096*8
    float* interA   = classSim + NROWS * KCLS;              // 4096
    float* threshA  = interA  + NROWS;
    float* posLossA = threshA + NROWS;
    float* rowPsum  = posLossA + NROWS;
    float* rowNsum  = rowPsum + NROWS;
    float* blkPart  = rowNsum + NROWS;                      // 64
    unsigned int* counter = (unsigned int*)(blkPart + 64);  // 1
    unsigned short* Xf = (unsigned short*)(counter + 16);   // 2 MB
    // total ws use: ~2.4 MB; counter zeroed by convert (3 dispatches early)

    convert_kernel<<<512, 256, 0, stream>>>(X, Xf, counter);

    dim3 grid(32, 32);
    gemm_pass_kernel<1><<<grid, 256, 0, stream>>>(Xf, nullptr, nullptr,
                                                  sumPart, sqPart, classSim);

    stats_kernel<<<NROWS / 256, 256, 0, stream>>>(sumPart, sqPart, classSim,
                                                  interA, threshA, posLossA,
                                                  rowPsum, rowNsum);

    gemm_pass_kernel<0><<<grid, 256, 0, stream>>>(Xf, interA, threshA,
                                                  cntPart, nlsPart, nullptr);

    finalAB_kernel<<<16, 256, 0, stream>>>(cntPart, nlsPart, posLossA,
                                           rowPsum, rowNsum, blkPart, counter,
                                           (float*)d_out);
}